// Round 20
// baseline (127.763 us; speedup 1.0000x reference)
//
#include <hip/hip_runtime.h>

// SelfAttention: x[8,2048,512] f32, W[3,512,512] f32 -> out[8,2048,512] f32
// scale = 1/sqrt(64) = 0.125
//
// R20: LDS-repack epilogues for scores and pv. At 1 blk/CU the epilogue is
// serialized dead time, and both kernels wrote C as scalar stores (scores:
// 32 u16 stores/thread at stride 2048 = 32B runs, ~8.4M store instrs; pv:
// 16 f32 scalar stores, 64B runs). Fix: after mainloop the staging LDS is
// dead and exactly fits the C-tile (scores 256x256 bf16 = 128KB; pv 256x128
// f32 = 128KB) -> write (exp'd / normalized) values to LDS in C layout,
// barrier, read back row-wise, store 512B-contiguous u16x8/float4 runs.
// Mainloops + qkv + convert identical to R19 (124.0us).

typedef unsigned short u16;
typedef unsigned int u32;

using bf16x8 = __attribute__((ext_vector_type(8))) short;   // 8 bf16 (4 VGPRs)
using f32x4  = __attribute__((ext_vector_type(4))) float;
using u16x4  = __attribute__((ext_vector_type(4))) u16;
using u16x8  = __attribute__((ext_vector_type(8))) u16;

__device__ __forceinline__ u16 f2bf(float f) {
  u32 u = __float_as_uint(f);
  u32 r = (u + 0x7FFFu + ((u >> 16) & 1u)) >> 16;   // RNE
  return (u16)r;
}
__device__ __forceinline__ float bf2f(u16 h) {
  return __uint_as_float(((u32)h) << 16);
}

#define GLL16(src, dst)                                                        \
  __builtin_amdgcn_global_load_lds(                                            \
      (const __attribute__((address_space(1))) void*)(src),                    \
      (__attribute__((address_space(3))) void*)(dst), 16, 0, 0)

// ---------------------------------------------------------------------------
// 256x128 single-frag-set mainloop (qkv): 8 waves 4Mx2N, acc[4][4], 3-slot
// BK=32, gate vmcnt(3)+barrier. bounds(512,4), 72KB -> 2 blk/CU.
// ---------------------------------------------------------------------------
template <int K>
__device__ __forceinline__ void gemm8p_256x128(
    const u16* __restrict__ A0, const u16* __restrict__ B0,
    u16* lds, f32x4 (&acc)[4][4])
{
  const int tid = threadIdx.x;
  const int w = tid >> 6, l = tid & 63;
  const int wm = w >> 1, wn = w & 1;
  const int fr = l & 15;
  const int laneChunk = ((l >> 4) ^ ((fr >> 1) & 3)) << 3;
  const int laneA = (wm * 64 + fr) * 32 + laneChunk;
  const int laneB = (wn * 64 + fr) * 32 + laneChunk;
  u16* const ldsA = lds;                 // 3 slots x 8192 u16 (16 KB)
  u16* const ldsB = lds + 24576;         // 3 slots x 4096 u16 (8 KB)

  const int chunkS = ((tid & 3) ^ ((tid >> 3) & 3)) << 3;
  const int r0 = tid >> 2;               // 0..127
  const u16* const sA0 = A0 + (size_t)r0 * K + chunkS;
  const u16* const sA1 = A0 + (size_t)(r0 + 128) * K + chunkS;
  const u16* const sB0 = B0 + (size_t)r0 * K + chunkS;
  const int dOf = w * 512;

#define PSTAGE_A(j, slot) do {                                                 \
    u16* d_ = ldsA + (slot) * 8192 + dOf;                                      \
    GLL16(sA0 + (j) * 32, d_);                                                 \
    GLL16(sA1 + (j) * 32, d_ + 4096);                                          \
  } while (0)
#define PSTAGE_B(j, slot) do {                                                 \
    u16* d_ = ldsB + (slot) * 4096 + dOf;                                      \
    GLL16(sB0 + (j) * 32, d_);                                                 \
  } while (0)

  PSTAGE_B(0, 0); PSTAGE_A(0, 0);
  PSTAGE_B(1, 1); PSTAGE_A(1, 1);

  constexpr int NS = K / 32;
  int slot = 0;
  for (int j = 0; j < NS; ++j) {
    const int jn = (j + 2 < NS) ? (j + 2) : (NS - 1);
    int slotn = slot + 2; if (slotn >= 3) slotn -= 3;

    asm volatile("s_waitcnt vmcnt(3)\n\ts_barrier" ::: "memory");

    const u16* const Ab = ldsA + slot * 8192;
    const u16* const Bb = ldsB + slot * 4096;
    bf16x8 a[4], b[4];
#pragma unroll
    for (int i = 0; i < 4; ++i) a[i] = *(const bf16x8*)(Ab + laneA + i * 512);
#pragma unroll
    for (int i = 0; i < 4; ++i) b[i] = *(const bf16x8*)(Bb + laneB + i * 512);
    PSTAGE_B(jn, slotn);
    __builtin_amdgcn_s_setprio(1);
#pragma unroll
    for (int mi = 0; mi < 2; ++mi)
#pragma unroll
      for (int nj = 0; nj < 4; ++nj)
        acc[mi][nj] = __builtin_amdgcn_mfma_f32_16x16x32_bf16(a[mi], b[nj], acc[mi][nj], 0, 0, 0);
    __builtin_amdgcn_s_setprio(0);
    PSTAGE_A(jn, slotn);
    __builtin_amdgcn_s_setprio(1);
#pragma unroll
    for (int mi = 2; mi < 4; ++mi)
#pragma unroll
      for (int nj = 0; nj < 4; ++nj)
        acc[mi][nj] = __builtin_amdgcn_mfma_f32_16x16x32_bf16(a[mi], b[nj], acc[mi][nj], 0, 0, 0);
    __builtin_amdgcn_s_setprio(0);

    slot = (slot == 2) ? 0 : slot + 1;
  }
#undef PSTAGE_A
#undef PSTAGE_B
}

// ---------------------------------------------------------------------------
// 256x128 4-slot ping-pong mainloop (pv): frags[j+1] read during MFMA[j];
// stage slab j+3 into slot (j+3)&3; gate vmcnt(3) only. ROWSUM: acc5 +=
// A x ones (matrix-pipe rowsum). Staging uses first 96KB of lds.
// ---------------------------------------------------------------------------
template <int K>
__device__ __forceinline__ void gemm128_pp4(
    const u16* __restrict__ A0, const u16* __restrict__ B0,
    u16* lds, f32x4 (&acc)[4][4], f32x4 (&acc5)[4])
{
  const int tid = threadIdx.x;
  const int w = tid >> 6, l = tid & 63;
  const int wm = w >> 1, wn = w & 1;
  const int fr = l & 15;
  const int laneChunk = ((l >> 4) ^ ((fr >> 1) & 3)) << 3;
  const int laneA = (wm * 64 + fr) * 32 + laneChunk;
  const int laneB = (wn * 64 + fr) * 32 + laneChunk;
  u16* const ldsA = lds;                 // 4 slots x 8192 u16 (16 KB)
  u16* const ldsB = lds + 32768;         // 4 slots x 4096 u16 (8 KB)

  const int chunkS = ((tid & 3) ^ ((tid >> 3) & 3)) << 3;
  const int r0 = tid >> 2;               // 0..127
  const u16* const sA0 = A0 + (size_t)r0 * K + chunkS;
  const u16* const sA1 = A0 + (size_t)(r0 + 128) * K + chunkS;
  const u16* const sB0 = B0 + (size_t)r0 * K + chunkS;
  const int dOf = w * 512;

  bf16x8 bOnes;
#pragma unroll
  for (int i = 0; i < 8; ++i) bOnes[i] = (short)0x3F80;   // bf16 1.0

#define PSTAGE_A(j, slot) do {                                                 \
    u16* d_ = ldsA + (slot) * 8192 + dOf;                                      \
    GLL16(sA0 + (j) * 32, d_);                                                 \
    GLL16(sA1 + (j) * 32, d_ + 4096);                                          \
  } while (0)
#define PSTAGE_B(j, slot) do {                                                 \
    u16* d_ = ldsB + (slot) * 4096 + dOf;                                      \
    GLL16(sB0 + (j) * 32, d_);                                                 \
  } while (0)

  constexpr int NS = K / 32;
  bf16x8 aP[4], bP[4], aQ[4], bQ[4];     // statically-named ping-pong sets

  PSTAGE_B(0, 0); PSTAGE_A(0, 0);
  PSTAGE_B(1, 1); PSTAGE_A(1, 1);
  PSTAGE_B(2, 2); PSTAGE_A(2, 2);
  asm volatile("s_waitcnt vmcnt(6)\n\ts_barrier" ::: "memory");
#pragma unroll
  for (int i = 0; i < 4; ++i) aP[i] = *(const bf16x8*)(ldsA + laneA + i * 512);
#pragma unroll
  for (int i = 0; i < 4; ++i) bP[i] = *(const bf16x8*)(ldsB + laneB + i * 512);

#define KITER(jj, CA, CB, NA, NB) do {                                         \
    const int js_ = ((jj) + 3 < NS) ? (jj) + 3 : NS - 1;                       \
    const int sS_ = ((jj) + 3) & 3;                                            \
    const int sR_ = ((jj) + 1) & 3;                                            \
    asm volatile("s_waitcnt vmcnt(3)\n\ts_barrier" ::: "memory");              \
    const u16* const Ab_ = ldsA + sR_ * 8192;                                  \
    const u16* const Bb_ = ldsB + sR_ * 4096;                                  \
    _Pragma("unroll")                                                          \
    for (int i = 0; i < 4; ++i) NB[i] = *(const bf16x8*)(Bb_ + laneB + i * 512); \
    _Pragma("unroll")                                                          \
    for (int i = 0; i < 4; ++i) NA[i] = *(const bf16x8*)(Ab_ + laneA + i * 512); \
    PSTAGE_B(js_, sS_);                                                        \
    __builtin_amdgcn_s_setprio(1);                                             \
    _Pragma("unroll")                                                          \
    for (int mi = 0; mi < 2; ++mi)                                             \
      _Pragma("unroll")                                                        \
      for (int nj = 0; nj < 4; ++nj)                                           \
        acc[mi][nj] = __builtin_amdgcn_mfma_f32_16x16x32_bf16(                 \
            CA[mi], CB[nj], acc[mi][nj], 0, 0, 0);                             \
    __builtin_amdgcn_s_setprio(0);                                             \
    PSTAGE_A(js_, sS_);                                                        \
    __builtin_amdgcn_s_setprio(1);                                             \
    _Pragma("unroll")                                                          \
    for (int mi = 2; mi < 4; ++mi)                                             \
      _Pragma("unroll")                                                        \
      for (int nj = 0; nj < 4; ++nj)                                           \
        acc[mi][nj] = __builtin_amdgcn_mfma_f32_16x16x32_bf16(                 \
            CA[mi], CB[nj], acc[mi][nj], 0, 0, 0);                             \
    _Pragma("unroll")                                                          \
    for (int mi = 0; mi < 4; ++mi)                                             \
      acc5[mi] = __builtin_amdgcn_mfma_f32_16x16x32_bf16(                      \
          CA[mi], bOnes, acc5[mi], 0, 0, 0);                                   \
    __builtin_amdgcn_s_setprio(0);                                             \
  } while (0)

  for (int j = 0; j < NS; j += 2) {      // NS even; static reg names
    KITER(j, aP, bP, aQ, bQ);
    KITER(j + 1, aQ, bQ, aP, bP);
  }
#undef KITER
#undef PSTAGE_A
#undef PSTAGE_B
}

// ---------------------------------------------------------------------------
// 256x256 4-slot ping-pong mainloop (scores): gate vmcnt(4) only.
// LDS 128KB, 1 blk/CU.
// ---------------------------------------------------------------------------
template <int K>
__device__ __forceinline__ void gemm8p_256sq_pp4(
    const u16* __restrict__ A0, const u16* __restrict__ B0,
    u16* lds, f32x4 (&acc)[8][4])
{
  const int tid = threadIdx.x;
  const int w = tid >> 6, l = tid & 63;
  const int wm = w >> 2, wn = w & 3;
  const int fr = l & 15;
  const int laneChunk = ((l >> 4) ^ ((fr >> 1) & 3)) << 3;
  const int laneA = (wm * 128 + fr) * 32 + laneChunk;
  const int laneB = (wn * 64 + fr) * 32 + laneChunk;
  u16* const ldsA = lds;                 // 4 slots x 8192 u16 (16 KB)
  u16* const ldsB = lds + 32768;         // 4 slots x 8192 u16 (16 KB)

  const int chunkS = ((tid & 3) ^ ((tid >> 3) & 3)) << 3;
  const int r0 = tid >> 2;               // 0..127
  const u16* const sA0 = A0 + (size_t)r0 * K + chunkS;
  const u16* const sA1 = A0 + (size_t)(r0 + 128) * K + chunkS;
  const u16* const sB0 = B0 + (size_t)r0 * K + chunkS;
  const u16* const sB1 = B0 + (size_t)(r0 + 128) * K + chunkS;
  const int dOf = w * 512;

#define SSTAGE_A(j, slot) do {                                                 \
    u16* d_ = ldsA + (slot) * 8192 + dOf;                                      \
    GLL16(sA0 + (j) * 32, d_);                                                 \
    GLL16(sA1 + (j) * 32, d_ + 4096);                                          \
  } while (0)
#define SSTAGE_B(j, slot) do {                                                 \
    u16* d_ = ldsB + (slot) * 8192 + dOf;                                      \
    GLL16(sB0 + (j) * 32, d_);                                                 \
    GLL16(sB1 + (j) * 32, d_ + 4096);                                          \
  } while (0)

  constexpr int NS = K / 32;
  bf16x8 bP[4], aP0[4], aP1[4], bQ[4], aQ0[4], aQ1[4];

  SSTAGE_B(0, 0); SSTAGE_A(0, 0);
  SSTAGE_B(1, 1); SSTAGE_A(1, 1);
  SSTAGE_B(2, 2); SSTAGE_A(2, 2);
  asm volatile("s_waitcnt vmcnt(8)\n\ts_barrier" ::: "memory");
#pragma unroll
  for (int i = 0; i < 4; ++i) bP[i]  = *(const bf16x8*)(ldsB + laneB + i * 512);
#pragma unroll
  for (int i = 0; i < 4; ++i) aP0[i] = *(const bf16x8*)(ldsA + laneA + i * 512);
#pragma unroll
  for (int i = 0; i < 4; ++i) aP1[i] = *(const bf16x8*)(ldsA + laneA + (4 + i) * 512);

#define SITER(jj, CB, CA0, CA1, NB, NA0, NA1) do {                             \
    const int js_ = ((jj) + 3 < NS) ? (jj) + 3 : NS - 1;                       \
    const int sS_ = ((jj) + 3) & 3;                                            \
    const int sR_ = ((jj) + 1) & 3;                                            \
    asm volatile("s_waitcnt vmcnt(4)\n\ts_barrier" ::: "memory");              \
    const u16* const Ab_ = ldsA + sR_ * 8192;                                  \
    const u16* const Bb_ = ldsB + sR_ * 8192;                                  \
    _Pragma("unroll")                                                          \
    for (int i = 0; i < 4; ++i) NB[i]  = *(const bf16x8*)(Bb_ + laneB + i * 512); \
    _Pragma("unroll")                                                          \
    for (int i = 0; i < 4; ++i) NA0[i] = *(const bf16x8*)(Ab_ + laneA + i * 512); \
    SSTAGE_A(js_, sS_);                                                        \
    __builtin_amdgcn_s_setprio(1);                                             \
    _Pragma("unroll")                                                          \
    for (int mi = 0; mi < 4; ++mi)                                             \
      _Pragma("unroll")                                                        \
      for (int nj = 0; nj < 4; ++nj)                                           \
        acc[mi][nj] = __builtin_amdgcn_mfma_f32_16x16x32_bf16(                 \
            CA0[mi], CB[nj], acc[mi][nj], 0, 0, 0);                            \
    __builtin_amdgcn_s_setprio(0);                                             \
    _Pragma("unroll")                                                          \
    for (int i = 0; i < 4; ++i) NA1[i] = *(const bf16x8*)(Ab_ + laneA + (4 + i) * 512); \
    SSTAGE_B(js_, sS_);                                                        \
    __builtin_amdgcn_s_setprio(1);                                             \
    _Pragma("unroll")                                                          \
    for (int mi = 0; mi < 4; ++mi)                                             \
      _Pragma("unroll")                                                        \
      for (int nj = 0; nj < 4; ++nj)                                           \
        acc[4 + mi][nj] = __builtin_amdgcn_mfma_f32_16x16x32_bf16(             \
            CA1[mi], CB[nj], acc[4 + mi][nj], 0, 0, 0);                        \
    __builtin_amdgcn_s_setprio(0);                                             \
  } while (0)

  for (int j = 0; j < NS; j += 2) {
    SITER(j, bP, aP0, aP1, bQ, aQ0, aQ1);
    SITER(j + 1, bQ, aQ0, aQ1, bP, aP0, aP1);
  }
#undef SITER
#undef SSTAGE_A
#undef SSTAGE_B
}

// ---------------------------------------------------------------------------
// Kernels
// ---------------------------------------------------------------------------

// convert x f32 -> bf16 (XCD-ownership swizzle: id&7 = batch).
__global__ void convert_x_kernel(const float* __restrict__ x, u16* __restrict__ xb) {
  const int b = blockIdx.x & 7, t = blockIdx.x >> 3;   // t: 0..1023
  const size_t i = ((size_t)b * 1024 + t) * 256 + threadIdx.x;
  float4 f = ((const float4*)x)[i];
  u16x4 o = { f2bf(f.x), f2bf(f.y), f2bf(f.z), f2bf(f.w) };
  ((u16x4*)xb)[i] = o;
}

// W[m][d][e] f32 -> Wt[m][e][d] bf16 (LDS-tiled transpose)
__global__ void convw_kernel(const float* __restrict__ W, u16* __restrict__ wT) {
  __shared__ float tile[32][33];
  const int mtx = blockIdx.z;
  const int e0 = blockIdx.x * 32, d0 = blockIdx.y * 32;
  const int tx = threadIdx.x, ty = threadIdx.y;
  const float* Wm = W + (size_t)mtx * 262144;
#pragma unroll
  for (int i = 0; i < 32; i += 8)
    tile[ty + i][tx] = Wm[(size_t)(d0 + ty + i) * 512 + e0 + tx];
  __syncthreads();
  u16* T = wT + (size_t)mtx * 262144;
#pragma unroll
  for (int i = 0; i < 32; i += 8)
    T[(size_t)(e0 + ty + i) * 512 + d0 + tx] = f2bf(tile[tx][ty + i]);
}

// QKV: xb[16384,512] . wT[1536,512]^T via 256x128 tiles (single frag set).
// Swizzle: xcd = id&7 owns batch xcd's m-rows: x 2MB + wT 1.5MB L2-resident.
__global__ __launch_bounds__(512, 4) void gemm_qkv128_kernel(
    const u16* __restrict__ xb, const u16* __restrict__ wT,
    u16* __restrict__ qb, u16* __restrict__ kb, u16* __restrict__ vt)
{
  __shared__ __align__(16) u16 lds[36864];   // 72 KB
  const int id = blockIdx.x;                 // 768 blocks
  const int xcd = id & 7, t = id >> 3;       // t: 0..95
  const int n0 = (t % 12) * 128;
  const int m0 = (xcd * 8 + t / 12) * 256;
  f32x4 acc[4][4] = {};
  gemm8p_256x128<512>(xb + (size_t)m0 * 512, wT + (size_t)n0 * 512, lds, acc);

  const int tid = threadIdx.x, w = tid >> 6, l = tid & 63;
  const int wm = w >> 1, wn = w & 1;
  const int which = n0 >> 9;                 // 0=q 1=k 2=v
  const int eb = (n0 & 511) + wn * 64 + (l & 15);
  const int rb = m0 + wm * 64 + (l >> 4) * 4;
  if (which < 2) {
    u16* dst = which ? kb : qb;
#pragma unroll
    for (int mi = 0; mi < 4; ++mi)
#pragma unroll
      for (int nj = 0; nj < 4; ++nj) {
        const int row = rb + mi * 16;
        const int col = eb + nj * 16;
#pragma unroll
        for (int r = 0; r < 4; ++r)
          dst[(size_t)(row + r) * 512 + col] = f2bf(acc[mi][nj][r]);
      }
  } else {
#pragma unroll
    for (int mi = 0; mi < 4; ++mi)
#pragma unroll
      for (int nj = 0; nj < 4; ++nj) {
        const int s = rb + mi * 16;            // global row (b*2048+s)
        const int b = s >> 11, sl = s & 2047;
        const int e = eb + nj * 16;
        u16x4 pk;
#pragma unroll
        for (int r = 0; r < 4; ++r) pk[r] = f2bf(acc[mi][nj][r]);
        *(u16x4*)(vt + (size_t)b * 1048576 + (size_t)e * 2048 + sl) = pk;
      }
  }
}

// P[z] = exp(Q[z].K[z]^T * 0.125) -> bf16 (unnormalized; pv divides by
// rowsum). 256x256 4-slot pp tiles; epilogue repacks C through the (dead)
// staging LDS: exp'd values written in C layout, read back row-wise, stored
// as u16x8 (512B contiguous runs vs 32B scalar scatter).
__global__ __launch_bounds__(512, 2) void gemm_scores256_kernel(
    const u16* __restrict__ qb, const u16* __restrict__ kb, u16* __restrict__ attn)
{
  __shared__ __align__(16) u16 lds[65536];   // 128 KB (staging; then C-tile)
  const int id = blockIdx.x;                 // 512 blocks
  const int z = id & 7, t = id >> 3;         // t: 0..63
  const int n0 = (t & 7) * 256;
  const int m0 = (t >> 3) * 256;
  f32x4 acc[8][4] = {};
  gemm8p_256sq_pp4<512>(qb + (size_t)z * 1048576 + (size_t)m0 * 512,
                        kb + (size_t)z * 1048576 + (size_t)n0 * 512, lds, acc);

  const int tid = threadIdx.x, w = tid >> 6, l = tid & 63;
  const int wm = w >> 2, wn = w & 3;

  // drain tail GLL dups + all LDS ops before reusing lds as C-tile
  asm volatile("s_waitcnt vmcnt(0) lgkmcnt(0)\n\ts_barrier" ::: "memory");

  // write exp'd C to LDS in [row][col] layout (256 x 256 u16)
  const int lr0 = wm * 128 + (l >> 4) * 4;
  const int lc0 = wn * 64 + (l & 15);
#pragma unroll
  for (int mi = 0; mi < 8; ++mi)
#pragma unroll
    for (int nj = 0; nj < 4; ++nj) {
      const int lrow = lr0 + mi * 16;
      const int lcol = lc0 + nj * 16;
#pragma unroll
      for (int r = 0; r < 4; ++r)
        lds[(lrow + r) * 256 + lcol] = f2bf(__expf(acc[mi][nj][r] * 0.125f));
    }
  __syncthreads();

  // coalesced store: per iter 16 rows x 32 lanes x 8 u16 (512B runs)
  u16* C = attn + (size_t)z * 4194304;
  const int rr = tid >> 5;                    // 0..15
  const int cc = (tid & 31) * 8;              // 0..248
#pragma unroll
  for (int i = 0; i < 16; ++i) {
    const int lrow = i * 16 + rr;
    u16x8 v = *(const u16x8*)(lds + lrow * 256 + cc);
    *(u16x8*)(C + (size_t)(m0 + lrow) * 2048 + n0 + cc) = v;
  }
}

// out[z] = (P[z].V[z]) / rowsum. 4-slot pp mainloop + MFMA rowsum
// (acc5 += A x ones; per-row sum lands on the normalizing lane).
// Epilogue repacks normalized f32 C-tile (256x128 = 128KB) through LDS.
__global__ __launch_bounds__(512, 2) void gemm_pv8p_kernel(
    const u16* __restrict__ attn, const u16* __restrict__ vt, float* __restrict__ out)
{
  __shared__ __align__(16) u16 lds[65536];   // 128 KB (96KB staging; then C)
  const int id = blockIdx.x;                 // 256 blocks
  const int z = id & 7;                      // id%8 = XCD (T1): one z per XCD
  const int j = id >> 3;                     // 0..31
  const int n0 = (j & 3) * 128;              // 4 n-tiles
  const int m0 = (j >> 2) * 256;             // 8 m-tiles
  f32x4 acc[4][4] = {};
  f32x4 acc5[4] = {};
  gemm128_pp4<2048>(attn + (size_t)z * 4194304 + (size_t)m0 * 2048,
                    vt + (size_t)z * 1048576 + (size_t)n0 * 2048, lds, acc, acc5);

  const int tid = threadIdx.x, w = tid >> 6, l = tid & 63;
  const int wm = w >> 1, wn = w & 1;

  asm volatile("s_waitcnt vmcnt(0) lgkmcnt(0)\n\ts_barrier" ::: "memory");

  // write normalized C to LDS in [row][col] layout (256 x 128 f32)
  float* ldsF = (float*)lds;
  const int lr0 = wm * 64 + (l >> 4) * 4;
  const int lc0 = wn * 64 + (l & 15);
#pragma unroll
  for (int mi = 0; mi < 4; ++mi)
#pragma unroll
    for (int r = 0; r < 4; ++r) {
      const float inv = 1.f / acc5[mi][r];
      const int lrow = lr0 + mi * 16 + r;
#pragma unroll
      for (int nj = 0; nj < 4; ++nj)
        ldsF[lrow * 128 + lc0 + nj * 16] = acc[mi][nj][r] * inv;
    }
  __syncthreads();

  // coalesced store: per iter 16 rows x 32 lanes x 4 f32 (512B runs)
  float* C = out + (size_t)z * 1048576;
  const int rr = tid >> 5;                    // 0..15
  const int cc = (tid & 31) * 4;              // 0..124
#pragma unroll
  for (int i = 0; i < 16; ++i) {
    const int lrow = i * 16 + rr;
    f32x4 v = *(const f32x4*)(ldsF + lrow * 128 + cc);
    *(f32x4*)(C + (size_t)(m0 + lrow) * 512 + n0 + cc) = v;
  }
}

// ---------------------------------------------------------------------------
extern "C" void kernel_launch(void* const* d_in, const int* in_sizes, int n_in,
                              void* d_out, int out_size, void* d_ws, size_t ws_size,
                              hipStream_t stream) {
  const float* x = (const float*)d_in[0];   // [8,2048,512]
  const float* W = (const float*)d_in[1];   // [3,512,512]
  float* out = (float*)d_out;               // [8,2048,512]

  if (ws_size < 117440512) return;          // 112 MiB needed
  u16* wsu  = (u16*)d_ws;
  u16* qb   = wsu;
  u16* kb   = qb + 8388608;
  u16* vt   = kb + 8388608;
  u16* attn = vt + 8388608;
  u16* xb   = attn;                         // alias: dead before scores written
  u16* wT   = attn + 8388608;               // alias: dead before scores written

  convert_x_kernel<<<8192, 256, 0, stream>>>(x, xb);
  convw_kernel<<<dim3(16, 16, 3), dim3(32, 8), 0, stream>>>(W, wT);
  gemm_qkv128_kernel<<<768, 512, 0, stream>>>(xb, wT, qb, kb, vt);
  gemm_scores256_kernel<<<512, 512, 0, stream>>>(qb, kb, attn);
  gemm_pv8p_kernel<<<256, 512, 0, stream>>>(attn, vt, out);
}

// Round 21
// 123.935 us; speedup vs baseline: 1.0309x; 1.0309x over previous
//
#include <hip/hip_runtime.h>

// SelfAttention: x[8,2048,512] f32, W[3,512,512] f32 -> out[8,2048,512] f32
// scale = 1/sqrt(64) = 0.125
//
// FINAL (= R19, best measured 123.9us): R20's LDS-repack epilogue reverted
// (introduced 1M bank conflicts - 512B row stride + scalar u16 LDS writes -
// and the epilogues were never store-bound; counters showed no WRITE delta).
//
// Structure: bf16 MFMA pipeline, 5 kernels.
//  convert_x (XCD-batch swizzle) | convw (transpose) |
//  qkv: 256x128 3-slot counted-vmcnt loop, 2 blk/CU |
//  scores: 256x256 4-slot register-ping-pong loop, exp(s/8) unnormalized |
//  pv: 256x128 4-slot ping-pong + MFMA rowsum (acc5 += A x ones),
//      normalizes in epilogue (softmax fully fused into the GEMMs).

typedef unsigned short u16;
typedef unsigned int u32;

using bf16x8 = __attribute__((ext_vector_type(8))) short;   // 8 bf16 (4 VGPRs)
using f32x4  = __attribute__((ext_vector_type(4))) float;
using u16x4  = __attribute__((ext_vector_type(4))) u16;

__device__ __forceinline__ u16 f2bf(float f) {
  u32 u = __float_as_uint(f);
  u32 r = (u + 0x7FFFu + ((u >> 16) & 1u)) >> 16;   // RNE
  return (u16)r;
}
__device__ __forceinline__ float bf2f(u16 h) {
  return __uint_as_float(((u32)h) << 16);
}

#define GLL16(src, dst)                                                        \
  __builtin_amdgcn_global_load_lds(                                            \
      (const __attribute__((address_space(1))) void*)(src),                    \
      (__attribute__((address_space(3))) void*)(dst), 16, 0, 0)

// ---------------------------------------------------------------------------
// 256x128 single-frag-set mainloop (qkv): 8 waves 4Mx2N, acc[4][4], 3-slot
// BK=32, gate vmcnt(3)+barrier. bounds(512,4), 72KB -> 2 blk/CU.
// ---------------------------------------------------------------------------
template <int K>
__device__ __forceinline__ void gemm8p_256x128(
    const u16* __restrict__ A0, const u16* __restrict__ B0,
    u16* lds, f32x4 (&acc)[4][4])
{
  const int tid = threadIdx.x;
  const int w = tid >> 6, l = tid & 63;
  const int wm = w >> 1, wn = w & 1;
  const int fr = l & 15;
  const int laneChunk = ((l >> 4) ^ ((fr >> 1) & 3)) << 3;
  const int laneA = (wm * 64 + fr) * 32 + laneChunk;
  const int laneB = (wn * 64 + fr) * 32 + laneChunk;
  u16* const ldsA = lds;                 // 3 slots x 8192 u16 (16 KB)
  u16* const ldsB = lds + 24576;         // 3 slots x 4096 u16 (8 KB)

  const int chunkS = ((tid & 3) ^ ((tid >> 3) & 3)) << 3;
  const int r0 = tid >> 2;               // 0..127
  const u16* const sA0 = A0 + (size_t)r0 * K + chunkS;
  const u16* const sA1 = A0 + (size_t)(r0 + 128) * K + chunkS;
  const u16* const sB0 = B0 + (size_t)r0 * K + chunkS;
  const int dOf = w * 512;

#define PSTAGE_A(j, slot) do {                                                 \
    u16* d_ = ldsA + (slot) * 8192 + dOf;                                      \
    GLL16(sA0 + (j) * 32, d_);                                                 \
    GLL16(sA1 + (j) * 32, d_ + 4096);                                          \
  } while (0)
#define PSTAGE_B(j, slot) do {                                                 \
    u16* d_ = ldsB + (slot) * 4096 + dOf;                                      \
    GLL16(sB0 + (j) * 32, d_);                                                 \
  } while (0)

  PSTAGE_B(0, 0); PSTAGE_A(0, 0);
  PSTAGE_B(1, 1); PSTAGE_A(1, 1);

  constexpr int NS = K / 32;
  int slot = 0;
  for (int j = 0; j < NS; ++j) {
    const int jn = (j + 2 < NS) ? (j + 2) : (NS - 1);
    int slotn = slot + 2; if (slotn >= 3) slotn -= 3;

    asm volatile("s_waitcnt vmcnt(3)\n\ts_barrier" ::: "memory");

    const u16* const Ab = ldsA + slot * 8192;
    const u16* const Bb = ldsB + slot * 4096;
    bf16x8 a[4], b[4];
#pragma unroll
    for (int i = 0; i < 4; ++i) a[i] = *(const bf16x8*)(Ab + laneA + i * 512);
#pragma unroll
    for (int i = 0; i < 4; ++i) b[i] = *(const bf16x8*)(Bb + laneB + i * 512);
    PSTAGE_B(jn, slotn);
    __builtin_amdgcn_s_setprio(1);
#pragma unroll
    for (int mi = 0; mi < 2; ++mi)
#pragma unroll
      for (int nj = 0; nj < 4; ++nj)
        acc[mi][nj] = __builtin_amdgcn_mfma_f32_16x16x32_bf16(a[mi], b[nj], acc[mi][nj], 0, 0, 0);
    __builtin_amdgcn_s_setprio(0);
    PSTAGE_A(jn, slotn);
    __builtin_amdgcn_s_setprio(1);
#pragma unroll
    for (int mi = 2; mi < 4; ++mi)
#pragma unroll
      for (int nj = 0; nj < 4; ++nj)
        acc[mi][nj] = __builtin_amdgcn_mfma_f32_16x16x32_bf16(a[mi], b[nj], acc[mi][nj], 0, 0, 0);
    __builtin_amdgcn_s_setprio(0);

    slot = (slot == 2) ? 0 : slot + 1;
  }
#undef PSTAGE_A
#undef PSTAGE_B
}

// ---------------------------------------------------------------------------
// 256x128 4-slot ping-pong mainloop (pv): frags[j+1] read during MFMA[j];
// stage slab j+3 into slot (j+3)&3; gate vmcnt(3) only (4-slot: read slot
// rewritten 4 slabs later). ROWSUM: acc5 += A x ones (matrix-pipe rowsum).
// LDS 96KB; bounds(512,2) (pv grid 256 = 1 blk/CU anyway).
// ---------------------------------------------------------------------------
template <int K>
__device__ __forceinline__ void gemm128_pp4(
    const u16* __restrict__ A0, const u16* __restrict__ B0,
    u16* lds, f32x4 (&acc)[4][4], f32x4 (&acc5)[4])
{
  const int tid = threadIdx.x;
  const int w = tid >> 6, l = tid & 63;
  const int wm = w >> 1, wn = w & 1;
  const int fr = l & 15;
  const int laneChunk = ((l >> 4) ^ ((fr >> 1) & 3)) << 3;
  const int laneA = (wm * 64 + fr) * 32 + laneChunk;
  const int laneB = (wn * 64 + fr) * 32 + laneChunk;
  u16* const ldsA = lds;                 // 4 slots x 8192 u16 (16 KB)
  u16* const ldsB = lds + 32768;         // 4 slots x 4096 u16 (8 KB)

  const int chunkS = ((tid & 3) ^ ((tid >> 3) & 3)) << 3;
  const int r0 = tid >> 2;               // 0..127
  const u16* const sA0 = A0 + (size_t)r0 * K + chunkS;
  const u16* const sA1 = A0 + (size_t)(r0 + 128) * K + chunkS;
  const u16* const sB0 = B0 + (size_t)r0 * K + chunkS;
  const int dOf = w * 512;

  bf16x8 bOnes;
#pragma unroll
  for (int i = 0; i < 8; ++i) bOnes[i] = (short)0x3F80;   // bf16 1.0

#define PSTAGE_A(j, slot) do {                                                 \
    u16* d_ = ldsA + (slot) * 8192 + dOf;                                      \
    GLL16(sA0 + (j) * 32, d_);                                                 \
    GLL16(sA1 + (j) * 32, d_ + 4096);                                          \
  } while (0)
#define PSTAGE_B(j, slot) do {                                                 \
    u16* d_ = ldsB + (slot) * 4096 + dOf;                                      \
    GLL16(sB0 + (j) * 32, d_);                                                 \
  } while (0)

  constexpr int NS = K / 32;
  bf16x8 aP[4], bP[4], aQ[4], bQ[4];     // statically-named ping-pong sets

  PSTAGE_B(0, 0); PSTAGE_A(0, 0);
  PSTAGE_B(1, 1); PSTAGE_A(1, 1);
  PSTAGE_B(2, 2); PSTAGE_A(2, 2);
  asm volatile("s_waitcnt vmcnt(6)\n\ts_barrier" ::: "memory");
#pragma unroll
  for (int i = 0; i < 4; ++i) aP[i] = *(const bf16x8*)(ldsA + laneA + i * 512);
#pragma unroll
  for (int i = 0; i < 4; ++i) bP[i] = *(const bf16x8*)(ldsB + laneB + i * 512);

#define KITER(jj, CA, CB, NA, NB) do {                                         \
    const int js_ = ((jj) + 3 < NS) ? (jj) + 3 : NS - 1;                       \
    const int sS_ = ((jj) + 3) & 3;                                            \
    const int sR_ = ((jj) + 1) & 3;                                            \
    asm volatile("s_waitcnt vmcnt(3)\n\ts_barrier" ::: "memory");              \
    const u16* const Ab_ = ldsA + sR_ * 8192;                                  \
    const u16* const Bb_ = ldsB + sR_ * 4096;                                  \
    _Pragma("unroll")                                                          \
    for (int i = 0; i < 4; ++i) NB[i] = *(const bf16x8*)(Bb_ + laneB + i * 512); \
    _Pragma("unroll")                                                          \
    for (int i = 0; i < 4; ++i) NA[i] = *(const bf16x8*)(Ab_ + laneA + i * 512); \
    PSTAGE_B(js_, sS_);                                                        \
    __builtin_amdgcn_s_setprio(1);                                             \
    _Pragma("unroll")                                                          \
    for (int mi = 0; mi < 2; ++mi)                                             \
      _Pragma("unroll")                                                        \
      for (int nj = 0; nj < 4; ++nj)                                           \
        acc[mi][nj] = __builtin_amdgcn_mfma_f32_16x16x32_bf16(                 \
            CA[mi], CB[nj], acc[mi][nj], 0, 0, 0);                             \
    __builtin_amdgcn_s_setprio(0);                                             \
    PSTAGE_A(js_, sS_);                                                        \
    __builtin_amdgcn_s_setprio(1);                                             \
    _Pragma("unroll")                                                          \
    for (int mi = 2; mi < 4; ++mi)                                             \
      _Pragma("unroll")                                                        \
      for (int nj = 0; nj < 4; ++nj)                                           \
        acc[mi][nj] = __builtin_amdgcn_mfma_f32_16x16x32_bf16(                 \
            CA[mi], CB[nj], acc[mi][nj], 0, 0, 0);                             \
    _Pragma("unroll")                                                          \
    for (int mi = 0; mi < 4; ++mi)                                             \
      acc5[mi] = __builtin_amdgcn_mfma_f32_16x16x32_bf16(                      \
          CA[mi], bOnes, acc5[mi], 0, 0, 0);                                   \
    __builtin_amdgcn_s_setprio(0);                                             \
  } while (0)

  for (int j = 0; j < NS; j += 2) {      // NS even; static reg names
    KITER(j, aP, bP, aQ, bQ);
    KITER(j + 1, aQ, bQ, aP, bP);
  }
#undef KITER
#undef PSTAGE_A
#undef PSTAGE_B
}

// ---------------------------------------------------------------------------
// 256x256 4-slot ping-pong mainloop (scores): gate vmcnt(4) only.
// LDS 128KB, 1 blk/CU.
// ---------------------------------------------------------------------------
template <int K>
__device__ __forceinline__ void gemm8p_256sq_pp4(
    const u16* __restrict__ A0, const u16* __restrict__ B0,
    u16* lds, f32x4 (&acc)[8][4])
{
  const int tid = threadIdx.x;
  const int w = tid >> 6, l = tid & 63;
  const int wm = w >> 2, wn = w & 3;
  const int fr = l & 15;
  const int laneChunk = ((l >> 4) ^ ((fr >> 1) & 3)) << 3;
  const int laneA = (wm * 128 + fr) * 32 + laneChunk;
  const int laneB = (wn * 64 + fr) * 32 + laneChunk;
  u16* const ldsA = lds;                 // 4 slots x 8192 u16 (16 KB)
  u16* const ldsB = lds + 32768;         // 4 slots x 8192 u16 (16 KB)

  const int chunkS = ((tid & 3) ^ ((tid >> 3) & 3)) << 3;
  const int r0 = tid >> 2;               // 0..127
  const u16* const sA0 = A0 + (size_t)r0 * K + chunkS;
  const u16* const sA1 = A0 + (size_t)(r0 + 128) * K + chunkS;
  const u16* const sB0 = B0 + (size_t)r0 * K + chunkS;
  const u16* const sB1 = B0 + (size_t)(r0 + 128) * K + chunkS;
  const int dOf = w * 512;

#define SSTAGE_A(j, slot) do {                                                 \
    u16* d_ = ldsA + (slot) * 8192 + dOf;                                      \
    GLL16(sA0 + (j) * 32, d_);                                                 \
    GLL16(sA1 + (j) * 32, d_ + 4096);                                          \
  } while (0)
#define SSTAGE_B(j, slot) do {                                                 \
    u16* d_ = ldsB + (slot) * 8192 + dOf;                                      \
    GLL16(sB0 + (j) * 32, d_);                                                 \
    GLL16(sB1 + (j) * 32, d_ + 4096);                                          \
  } while (0)

  constexpr int NS = K / 32;
  bf16x8 bP[4], aP0[4], aP1[4], bQ[4], aQ0[4], aQ1[4];

  SSTAGE_B(0, 0); SSTAGE_A(0, 0);
  SSTAGE_B(1, 1); SSTAGE_A(1, 1);
  SSTAGE_B(2, 2); SSTAGE_A(2, 2);
  asm volatile("s_waitcnt vmcnt(8)\n\ts_barrier" ::: "memory");
#pragma unroll
  for (int i = 0; i < 4; ++i) bP[i]  = *(const bf16x8*)(ldsB + laneB + i * 512);
#pragma unroll
  for (int i = 0; i < 4; ++i) aP0[i] = *(const bf16x8*)(ldsA + laneA + i * 512);
#pragma unroll
  for (int i = 0; i < 4; ++i) aP1[i] = *(const bf16x8*)(ldsA + laneA + (4 + i) * 512);

#define SITER(jj, CB, CA0, CA1, NB, NA0, NA1) do {                             \
    const int js_ = ((jj) + 3 < NS) ? (jj) + 3 : NS - 1;                       \
    const int sS_ = ((jj) + 3) & 3;                                            \
    const int sR_ = ((jj) + 1) & 3;                                            \
    asm volatile("s_waitcnt vmcnt(4)\n\ts_barrier" ::: "memory");              \
    const u16* const Ab_ = ldsA + sR_ * 8192;                                  \
    const u16* const Bb_ = ldsB + sR_ * 8192;                                  \
    _Pragma("unroll")                                                          \
    for (int i = 0; i < 4; ++i) NB[i]  = *(const bf16x8*)(Bb_ + laneB + i * 512); \
    _Pragma("unroll")                                                          \
    for (int i = 0; i < 4; ++i) NA0[i] = *(const bf16x8*)(Ab_ + laneA + i * 512); \
    SSTAGE_A(js_, sS_);                                                        \
    __builtin_amdgcn_s_setprio(1);                                             \
    _Pragma("unroll")                                                          \
    for (int mi = 0; mi < 4; ++mi)                                             \
      _Pragma("unroll")                                                        \
      for (int nj = 0; nj < 4; ++nj)                                           \
        acc[mi][nj] = __builtin_amdgcn_mfma_f32_16x16x32_bf16(                 \
            CA0[mi], CB[nj], acc[mi][nj], 0, 0, 0);                            \
    __builtin_amdgcn_s_setprio(0);                                             \
    _Pragma("unroll")                                                          \
    for (int i = 0; i < 4; ++i) NA1[i] = *(const bf16x8*)(Ab_ + laneA + (4 + i) * 512); \
    SSTAGE_B(js_, sS_);                                                        \
    __builtin_amdgcn_s_setprio(1);                                             \
    _Pragma("unroll")                                                          \
    for (int mi = 0; mi < 4; ++mi)                                             \
      _Pragma("unroll")                                                        \
      for (int nj = 0; nj < 4; ++nj)                                           \
        acc[4 + mi][nj] = __builtin_amdgcn_mfma_f32_16x16x32_bf16(             \
            CA1[mi], CB[nj], acc[4 + mi][nj], 0, 0, 0);                        \
    __builtin_amdgcn_s_setprio(0);                                             \
  } while (0)

  for (int j = 0; j < NS; j += 2) {
    SITER(j, bP, aP0, aP1, bQ, aQ0, aQ1);
    SITER(j + 1, bQ, aQ0, aQ1, bP, aP0, aP1);
  }
#undef SITER
#undef SSTAGE_A
#undef SSTAGE_B
}

// ---------------------------------------------------------------------------
// Kernels
// ---------------------------------------------------------------------------

// convert x f32 -> bf16 (XCD-ownership swizzle: id&7 = batch).
__global__ void convert_x_kernel(const float* __restrict__ x, u16* __restrict__ xb) {
  const int b = blockIdx.x & 7, t = blockIdx.x >> 3;   // t: 0..1023
  const size_t i = ((size_t)b * 1024 + t) * 256 + threadIdx.x;
  float4 f = ((const float4*)x)[i];
  u16x4 o = { f2bf(f.x), f2bf(f.y), f2bf(f.z), f2bf(f.w) };
  ((u16x4*)xb)[i] = o;
}

// W[m][d][e] f32 -> Wt[m][e][d] bf16 (LDS-tiled transpose)
__global__ void convw_kernel(const float* __restrict__ W, u16* __restrict__ wT) {
  __shared__ float tile[32][33];
  const int mtx = blockIdx.z;
  const int e0 = blockIdx.x * 32, d0 = blockIdx.y * 32;
  const int tx = threadIdx.x, ty = threadIdx.y;
  const float* Wm = W + (size_t)mtx * 262144;
#pragma unroll
  for (int i = 0; i < 32; i += 8)
    tile[ty + i][tx] = Wm[(size_t)(d0 + ty + i) * 512 + e0 + tx];
  __syncthreads();
  u16* T = wT + (size_t)mtx * 262144;
#pragma unroll
  for (int i = 0; i < 32; i += 8)
    T[(size_t)(e0 + ty + i) * 512 + d0 + tx] = f2bf(tile[tx][ty + i]);
}

// QKV: xb[16384,512] . wT[1536,512]^T via 256x128 tiles (single frag set).
// Swizzle: xcd = id&7 owns batch xcd's m-rows: x 2MB + wT 1.5MB L2-resident.
__global__ __launch_bounds__(512, 4) void gemm_qkv128_kernel(
    const u16* __restrict__ xb, const u16* __restrict__ wT,
    u16* __restrict__ qb, u16* __restrict__ kb, u16* __restrict__ vt)
{
  __shared__ __align__(16) u16 lds[36864];   // 72 KB
  const int id = blockIdx.x;                 // 768 blocks
  const int xcd = id & 7, t = id >> 3;       // t: 0..95
  const int n0 = (t % 12) * 128;
  const int m0 = (xcd * 8 + t / 12) * 256;
  f32x4 acc[4][4] = {};
  gemm8p_256x128<512>(xb + (size_t)m0 * 512, wT + (size_t)n0 * 512, lds, acc);

  const int tid = threadIdx.x, w = tid >> 6, l = tid & 63;
  const int wm = w >> 1, wn = w & 1;
  const int which = n0 >> 9;                 // 0=q 1=k 2=v
  const int eb = (n0 & 511) + wn * 64 + (l & 15);
  const int rb = m0 + wm * 64 + (l >> 4) * 4;
  if (which < 2) {
    u16* dst = which ? kb : qb;
#pragma unroll
    for (int mi = 0; mi < 4; ++mi)
#pragma unroll
      for (int nj = 0; nj < 4; ++nj) {
        const int row = rb + mi * 16;
        const int col = eb + nj * 16;
#pragma unroll
        for (int r = 0; r < 4; ++r)
          dst[(size_t)(row + r) * 512 + col] = f2bf(acc[mi][nj][r]);
      }
  } else {
#pragma unroll
    for (int mi = 0; mi < 4; ++mi)
#pragma unroll
      for (int nj = 0; nj < 4; ++nj) {
        const int s = rb + mi * 16;            // global row (b*2048+s)
        const int b = s >> 11, sl = s & 2047;
        const int e = eb + nj * 16;
        u16x4 pk;
#pragma unroll
        for (int r = 0; r < 4; ++r) pk[r] = f2bf(acc[mi][nj][r]);
        *(u16x4*)(vt + (size_t)b * 1048576 + (size_t)e * 2048 + sl) = pk;
      }
  }
}

// P[z] = exp(Q[z].K[z]^T * 0.125) -> bf16 (unnormalized; pv divides by
// rowsum). 256x256 4-slot pp tiles; 512 blocks = 2 rounds; z = id&7.
__global__ __launch_bounds__(512, 2) void gemm_scores256_kernel(
    const u16* __restrict__ qb, const u16* __restrict__ kb, u16* __restrict__ attn)
{
  __shared__ __align__(16) u16 lds[65536];   // 128 KB
  const int id = blockIdx.x;                 // 512 blocks
  const int z = id & 7, t = id >> 3;         // t: 0..63
  const int n0 = (t & 7) * 256;
  const int m0 = (t >> 3) * 256;
  f32x4 acc[8][4] = {};
  gemm8p_256sq_pp4<512>(qb + (size_t)z * 1048576 + (size_t)m0 * 512,
                        kb + (size_t)z * 1048576 + (size_t)n0 * 512, lds, acc);

  const int tid = threadIdx.x, w = tid >> 6, l = tid & 63;
  const int wm = w >> 2, wn = w & 3;
  u16* C = attn + (size_t)z * 4194304;
  const int rb = m0 + wm * 128 + (l >> 4) * 4;
  const int cb = n0 + wn * 64 + (l & 15);
#pragma unroll
  for (int mi = 0; mi < 8; ++mi)
#pragma unroll
    for (int nj = 0; nj < 4; ++nj) {
      const int row = rb + mi * 16;
      const int col = cb + nj * 16;
#pragma unroll
      for (int r = 0; r < 4; ++r)
        C[(size_t)(row + r) * 2048 + col] = f2bf(__expf(acc[mi][nj][r] * 0.125f));
    }
}

// out[z] = (P[z].V[z]) / rowsum. 4-slot pp mainloop + MFMA rowsum:
// acc5[mi] += A x ones; C-layout puts row rb+mi*16+(l>>4)*4+r's sum in
// acc5[mi][r] on the normalizing lane (no shfl).
__global__ __launch_bounds__(512, 2) void gemm_pv8p_kernel(
    const u16* __restrict__ attn, const u16* __restrict__ vt, float* __restrict__ out)
{
  __shared__ __align__(16) u16 lds[49152];   // 96 KB
  const int id = blockIdx.x;                 // 256 blocks
  const int z = id & 7;                      // id%8 = XCD (T1): one z per XCD
  const int j = id >> 3;                     // 0..31
  const int n0 = (j & 3) * 128;              // 4 n-tiles
  const int m0 = (j >> 2) * 256;             // 8 m-tiles
  f32x4 acc[4][4] = {};
  f32x4 acc5[4] = {};
  gemm128_pp4<2048>(attn + (size_t)z * 4194304 + (size_t)m0 * 2048,
                    vt + (size_t)z * 1048576 + (size_t)n0 * 2048, lds, acc, acc5);

  const int tid = threadIdx.x, w = tid >> 6, l = tid & 63;
  const int wm = w >> 1, wn = w & 1;
  const int rb = m0 + wm * 64 + (l >> 4) * 4;
  const int cb = n0 + wn * 64 + (l & 15);
  float* C = out + (size_t)z * 1048576;
#pragma unroll
  for (int mi = 0; mi < 4; ++mi)
#pragma unroll
    for (int r = 0; r < 4; ++r) {
      const float inv = 1.f / acc5[mi][r];
      const int row = rb + mi * 16 + r;
#pragma unroll
      for (int nj = 0; nj < 4; ++nj)
        C[(size_t)row * 512 + cb + nj * 16] = acc[mi][nj][r] * inv;
    }
}

// ---------------------------------------------------------------------------
extern "C" void kernel_launch(void* const* d_in, const int* in_sizes, int n_in,
                              void* d_out, int out_size, void* d_ws, size_t ws_size,
                              hipStream_t stream) {
  const float* x = (const float*)d_in[0];   // [8,2048,512]
  const float* W = (const float*)d_in[1];   // [3,512,512]
  float* out = (float*)d_out;               // [8,2048,512]

  if (ws_size < 117440512) return;          // 112 MiB needed
  u16* wsu  = (u16*)d_ws;
  u16* qb   = wsu;
  u16* kb   = qb + 8388608;
  u16* vt   = kb + 8388608;
  u16* attn = vt + 8388608;
  u16* xb   = attn;                         // alias: dead before scores written
  u16* wT   = attn + 8388608;               // alias: dead before scores written

  convert_x_kernel<<<8192, 256, 0, stream>>>(x, xb);
  convw_kernel<<<dim3(16, 16, 3), dim3(32, 8), 0, stream>>>(W, wT);
  gemm_qkv128_kernel<<<768, 512, 0, stream>>>(xb, wT, qb, kb, vt);
  gemm_scores256_kernel<<<512, 512, 0, stream>>>(qb, kb, attn);
  gemm_pv8p_kernel<<<256, 512, 0, stream>>>(attn, vt, out);
}